// Round 1
// baseline (739.790 us; speedup 1.0000x reference)
//
#include <hip/hip_runtime.h>

#define B_    64
#define NI    2048
#define DK    16
#define NO    32
#define DOUT  32
#define EPSQ  1e-7f

typedef unsigned u32x2 __attribute__((ext_vector_type(2)));
typedef unsigned u32x4 __attribute__((ext_vector_type(4)));

// ---------- helpers ----------
__device__ __forceinline__ unsigned pack2_bf16(float a, float b) {
    unsigned ua = __float_as_uint(a);
    unsigned ub = __float_as_uint(b);
    ua = (ua + 0x7fffu + ((ua >> 16) & 1u)) >> 16;   // RNE
    ub = (ub + 0x7fffu + ((ub >> 16) & 1u)) >> 16;
    return ua | (ub << 16);
}
__device__ __forceinline__ float bf_lo(unsigned w) { return __uint_as_float(w << 16); }
__device__ __forceinline__ float bf_hi(unsigned w) { return __uint_as_float(w & 0xffff0000u); }

// ============================================================
// FAST PATH
// u_hat layout (bf16/ushort): idx = (((b*NI + i)*4 + j)*NO + o)*8 + e, d = j*8+e
// ============================================================

constexpr int WSTRIDE = 516;   // 512 + 4 pad: one-time LDS read conflicts only

// Produce u_hat = einsum('oidk,bik->boid') once. Block = one i, 512 threads.
// U is write-once/read-once -> nontemporal stores keep W/x resident in L3.
__global__ __launch_bounds__(512)
void compute_uhat(const float* __restrict__ x, const float* __restrict__ W,
                  ushort* __restrict__ U)
{
    __shared__ float Ws[NO * WSTRIDE];   // 66048 B
    __shared__ float xs[B_ * DK];        // 4096 B
    const int i = blockIdx.x;
    const int t = threadIdx.x;

    // stage x[0:64, i, 0:16] (4 KB)
    if (t < 256) {
        const int b = t >> 2, k4 = t & 3;
        float4 v = *(const float4*)(x + ((size_t)b * NI + i) * DK + k4 * 4);
        *(float4*)&xs[b * DK + k4 * 4] = v;
    }

    // stage W[:, i, :, :] (64 KB) coalesced
    #pragma unroll
    for (int jj = 0; jj < 8; ++jj) {
        const int p  = t + 512 * jj;     // 0..4095
        const int oo = p >> 7;           // o
        const int cc = p & 127;          // float4 within o-row
        float4 v = ((const float4*)(W + ((size_t)oo * NI + i) * (DOUT * DK)))[cc];
        *(float4*)&Ws[oo * WSTRIDE + cc * 4] = v;
    }

    const int o  = t & 31;
    const int q  = (t >> 5) & 7;      // d = 4q .. 4q+3
    const int bh = t >> 8;            // 0/1

    __syncthreads();

    // one-time LDS -> regs: W[o,i,4q:4q+4,0:16] = 64 consecutive floats
    float w[64];
    {
        const float* wr = &Ws[o * WSTRIDE + q * 64];
        #pragma unroll
        for (int m = 0; m < 16; ++m) {
            float4 v = *(const float4*)(wr + 4 * m);
            w[4*m+0] = v.x; w[4*m+1] = v.y; w[4*m+2] = v.z; w[4*m+3] = v.w;
        }
    }

    const int j = q >> 1, half = q & 1;

    for (int bb = 0; bb < 32; ++bb) {
        const int b = bh * 32 + bb;
        const float4* xv = (const float4*)&xs[b * DK];
        const float4 x0 = xv[0], x1 = xv[1], x2 = xv[2], x3 = xv[3];

        float acc[4];
        #pragma unroll
        for (int dl = 0; dl < 4; ++dl) {
            const float* wr = &w[dl * 16];
            float a;
            a  = wr[0]  * x0.x + wr[1]  * x0.y + wr[2]  * x0.z + wr[3]  * x0.w;
            a += wr[4]  * x1.x + wr[5]  * x1.y + wr[6]  * x1.z + wr[7]  * x1.w;
            a += wr[8]  * x2.x + wr[9]  * x2.y + wr[10] * x2.z + wr[11] * x2.w;
            a += wr[12] * x3.x + wr[13] * x3.y + wr[14] * x3.z + wr[15] * x3.w;
            acc[dl] = a;
        }

        u32x2 pk;
        pk.x = pack2_bf16(acc[0], acc[1]);
        pk.y = pack2_bf16(acc[2], acc[3]);
        const size_t off = ((((size_t)b * NI + i) * 4 + j) * NO + o) * 8 + half * 4;
        __builtin_nontemporal_store(pk, (u32x2*)(U + off));   // 8-byte aligned
    }
}

// ============================================================
// r0 directly from W: s0[b,o,d] = (1/32) * sum_{i,k} W[o,i,d,k] x[b,i,k]
// Block = (o, i-segment). 512 threads: b = t&63 (lane), dq = wave id (uniform).
// W reads are wave-uniform -> scalar loads; x staged per 8-i chunk, padded.
// Runs BEFORE compute_uhat so W is L3-warm for it.
// ============================================================
constexpr int R0_SEG = 8;              // i-segments
constexpr int R0_IPB = NI / R0_SEG;    // 256 i per block
constexpr int R0_CH  = 8;              // i per staging chunk
constexpr int XPAD   = 20;             // padded floats per (i,b) row

__global__ __launch_bounds__(512)
void r0_sum(const float* __restrict__ x, const float* __restrict__ W,
            float* __restrict__ s0)
{
    __shared__ float xs[R0_CH * B_ * XPAD];   // 40960 B
    const int o    = blockIdx.x & (NO - 1);
    const int iseg = blockIdx.x >> 5;
    const int t    = threadIdx.x;
    const int b    = t & 63;
    const int dq   = __builtin_amdgcn_readfirstlane(t >> 6);  // wave-uniform 0..7

    float sacc[4] = {0.f, 0.f, 0.f, 0.f};

    const int i0base = iseg * R0_IPB;
    for (int c0 = 0; c0 < R0_IPB; c0 += R0_CH) {
        const int ibase = i0base + c0;
        __syncthreads();
        // stage x[:, ibase:ibase+8, :] = 2048 float4, coalesced-ish (16 full lines/instr)
        #pragma unroll
        for (int pp = 0; pp < 4; ++pp) {
            const int p  = t + 512 * pp;
            const int ii = p >> 8;
            const int bb = (p >> 2) & 63;
            const int m  = p & 3;
            float4 v = *(const float4*)(x + ((size_t)bb * NI + ibase + ii) * DK + m * 4);
            *(float4*)&xs[(ii * B_ + bb) * XPAD + m * 4] = v;
        }
        __syncthreads();

        for (int ii = 0; ii < R0_CH; ++ii) {
            const int i = ibase + ii;
            const float* wr = W + ((size_t)o * NI + i) * (DOUT * DK) + dq * 64;
            const float* xr = &xs[(ii * B_ + b) * XPAD];
            const float4 x0 = *(const float4*)(xr + 0);
            const float4 x1 = *(const float4*)(xr + 4);
            const float4 x2 = *(const float4*)(xr + 8);
            const float4 x3 = *(const float4*)(xr + 12);
            #pragma unroll
            for (int dl = 0; dl < 4; ++dl) {
                const float4 w0 = *(const float4*)(wr + dl * 16 + 0);
                const float4 w1 = *(const float4*)(wr + dl * 16 + 4);
                const float4 w2 = *(const float4*)(wr + dl * 16 + 8);
                const float4 w3 = *(const float4*)(wr + dl * 16 + 12);
                float a;
                a  = w0.x * x0.x + w0.y * x0.y + w0.z * x0.z + w0.w * x0.w;
                a += w1.x * x1.x + w1.y * x1.y + w1.z * x1.z + w1.w * x1.w;
                a += w2.x * x2.x + w2.y * x2.y + w2.z * x2.z + w2.w * x2.w;
                a += w3.x * x3.x + w3.y * x3.y + w3.z * x3.z + w3.w * x3.w;
                sacc[dl] += a;
            }
        }
    }

    #pragma unroll
    for (int m = 0; m < 4; ++m)
        atomicAdd(&s0[((size_t)b * NO + o) * DOUT + dq * 4 + m], sacc[m] * 0.03125f);
}

// ---------- per-i routing math (c from softmax, accumulate c*u) ----------
__device__ __forceinline__ void proc_one(const u32x4* cr, const float* vs, float* sacc)
{
    unsigned cw[16];
    #pragma unroll
    for (int jj = 0; jj < 4; ++jj) {
        cw[4*jj+0] = cr[jj].x; cw[4*jj+1] = cr[jj].y;
        cw[4*jj+2] = cr[jj].z; cw[4*jj+3] = cr[jj].w;
    }

    float l0 = 0.f, l1 = 0.f, l2 = 0.f, l3 = 0.f;
    #pragma unroll
    for (int m = 0; m < 16; m += 4) {
        const int d0 = (m >> 2) * 8;
        l0 = fmaf(vs[d0+0], bf_lo(cw[m+0]), l0);
        l0 = fmaf(vs[d0+1], bf_hi(cw[m+0]), l0);
        l1 = fmaf(vs[d0+2], bf_lo(cw[m+1]), l1);
        l1 = fmaf(vs[d0+3], bf_hi(cw[m+1]), l1);
        l2 = fmaf(vs[d0+4], bf_lo(cw[m+2]), l2);
        l2 = fmaf(vs[d0+5], bf_hi(cw[m+2]), l2);
        l3 = fmaf(vs[d0+6], bf_lo(cw[m+3]), l3);
        l3 = fmaf(vs[d0+7], bf_hi(cw[m+3]), l3);
    }
    const float logit = (l0 + l1) + (l2 + l3);

    // softmax over o = 32 lanes of this half-wave
    float mx = logit;
    #pragma unroll
    for (int msk = 16; msk >= 1; msk >>= 1) mx = fmaxf(mx, __shfl_xor(mx, msk));
    const float e = __expf(logit - mx);
    float ssum = e;
    #pragma unroll
    for (int msk = 16; msk >= 1; msk >>= 1) ssum += __shfl_xor(ssum, msk);
    const float c = e / ssum;

    #pragma unroll
    for (int m = 0; m < 16; ++m) {
        const int d0 = (m >> 2) * 8 + (m & 3) * 2;
        sacc[d0]     = fmaf(c, bf_lo(cw[m]), sacc[d0]);
        sacc[d0 + 1] = fmaf(c, bf_hi(cw[m]), sacc[d0 + 1]);
    }
}

// One routing iteration (r=1 or r=2) streaming u_hat.
// Prologue recomputes vs = squash(s0) [+ squash(s1) for R=2] in-block:
// kills the separate squash dispatches and the Vsum buffer.
constexpr int BPB = 16;               // blocks per b
constexpr int NIB = NI / BPB / 16;    // 8 group-iterations (16 i per group)

template<int R>
__global__ __launch_bounds__(256)
void routing_mid(const ushort* __restrict__ U, const float* __restrict__ sA,
                 const float* __restrict__ sB, float* __restrict__ s_out)
{
    __shared__ float sblk[NO * DOUT];     // swizzled: (o,d) at [o*32 + ((d+o)&31)]
    __shared__ float vsh[NO][DOUT + 1];   // +1 pad -> conflict-free column reads
    const int t  = threadIdx.x;
    const int b  = blockIdx.x >> 4;
    const int i0 = (blockIdx.x & (BPB - 1)) * (NI / BPB);

    // ---- vs (running v sum) into vsh: thread = (oo = t>>3, dg = t&7) ----
    {
        const int oo = t >> 3;
        const int dg = t & 7;
        float4 sv = *(const float4*)(sA + ((size_t)b * NO + oo) * DOUT + dg * 4);
        float sq = sv.x*sv.x + sv.y*sv.y + sv.z*sv.z + sv.w*sv.w;
        #pragma unroll
        for (int msk = 4; msk >= 1; msk >>= 1) sq += __shfl_xor(sq, msk);
        float sc = sq / (1.f + sq) * rsqrtf(sq + EPSQ);
        float v0 = sv.x * sc, v1 = sv.y * sc, v2 = sv.z * sc, v3 = sv.w * sc;
        if (R == 2) {
            float4 s2v = *(const float4*)(sB + ((size_t)b * NO + oo) * DOUT + dg * 4);
            float sq2 = s2v.x*s2v.x + s2v.y*s2v.y + s2v.z*s2v.z + s2v.w*s2v.w;
            #pragma unroll
            for (int msk = 4; msk >= 1; msk >>= 1) sq2 += __shfl_xor(sq2, msk);
            float sc2 = sq2 / (1.f + sq2) * rsqrtf(sq2 + EPSQ);
            v0 += s2v.x * sc2; v1 += s2v.y * sc2; v2 += s2v.z * sc2; v3 += s2v.w * sc2;
        }
        vsh[oo][dg*4+0] = v0; vsh[oo][dg*4+1] = v1;
        vsh[oo][dg*4+2] = v2; vsh[oo][dg*4+3] = v3;
    }
    for (int n = t; n < NO * DOUT; n += 256) sblk[n] = 0.f;
    __syncthreads();

    const int o  = t & 31;
    const int hw = t >> 5;            // 0..7

    float vs[DOUT];
    #pragma unroll
    for (int d = 0; d < DOUT; ++d) vs[d] = vsh[o][d];

    float sacc[DOUT];
    #pragma unroll
    for (int d = 0; d < DOUT; ++d) sacc[d] = 0.f;

    // per (b,i): 4*NO u32x4's; row j at [j*NO]; i+1 is +4*NO
    const u32x4* up = (const u32x4*)U + ((size_t)b * NI + i0 + 2 * hw) * (4 * NO) + o;
    const size_t step = (size_t)16 * 4 * NO;   // advance i by 16

    u32x4 cur[8];
    #pragma unroll
    for (int jj = 0; jj < 4; ++jj) {
        cur[jj]     = __builtin_nontemporal_load(up + jj * NO);
        cur[4 + jj] = __builtin_nontemporal_load(up + 4 * NO + jj * NO);
    }
    up += step;

    for (int ii = 0; ii < NIB; ++ii) {
        u32x4 nxt[8];
        if (ii + 1 < NIB) {           // uniform branch
            #pragma unroll
            for (int jj = 0; jj < 4; ++jj) {
                nxt[jj]     = __builtin_nontemporal_load(up + jj * NO);
                nxt[4 + jj] = __builtin_nontemporal_load(up + 4 * NO + jj * NO);
            }
            up += step;
        }

        proc_one(&cur[0], vs, sacc);
        proc_one(&cur[4], vs, sacc);

        #pragma unroll
        for (int jj = 0; jj < 8; ++jj) cur[jj] = nxt[jj];
    }

    // reduce the wave's two half-waves (same (b,o), disjoint i)
    #pragma unroll
    for (int d = 0; d < DOUT; ++d) sacc[d] += __shfl_xor(sacc[d], 32);

    if ((t & 32) == 0) {
        #pragma unroll
        for (int d = 0; d < DOUT; ++d)
            atomicAdd(&sblk[o * DOUT + ((d + o) & 31)], sacc[d]);  // conflict-free
    }
    __syncthreads();

    float* sp = s_out + (size_t)b * NO * DOUT;
    for (int n = t; n < NO * DOUT; n += 256) {
        const int oo = n >> 5, ds = n & 31;
        const int dd = (ds - oo) & 31;
        atomicAdd(&sp[oo * DOUT + dd], sblk[n]);
    }
}

// final v = squash(s2) -> out
__global__ __launch_bounds__(256)
void squash_final(const float* __restrict__ s, float* __restrict__ out)
{
    const int tid  = threadIdx.x;
    const int pair = blockIdx.x * 8 + (tid >> 5);
    const int d    = tid & 31;
    const int idx  = pair * DOUT + d;

    const float val = s[idx];
    float sq = val * val;
    #pragma unroll
    for (int msk = 16; msk >= 1; msk >>= 1) sq += __shfl_xor(sq, msk);

    const float scale = sq / (1.f + sq) * rsqrtf(sq + EPSQ);
    out[idx] = val * scale;
}

// v = squash(s); Vsum += v; last iteration writes v to out.  (fallback path)
__global__ __launch_bounds__(256)
void squash_update(const float* __restrict__ s, float* __restrict__ Vsum,
                   float* __restrict__ out, int last)
{
    const int tid  = threadIdx.x;
    const int pair = blockIdx.x * 8 + (tid >> 5);
    const int d    = tid & 31;
    const int idx  = pair * DOUT + d;

    const float val = s[idx];
    float sq = val * val;
    #pragma unroll
    for (int msk = 16; msk >= 1; msk >>= 1) sq += __shfl_xor(sq, msk);

    const float scale = sq / (1.f + sq) * rsqrtf(sq + EPSQ);
    const float v = val * scale;

    if (last) out[idx] = v;
    else      Vsum[idx] += v;
}

// ============================================================
// FALLBACK PATH (fused recompute; used if ws too small)
// ============================================================
constexpr int BTILE  = 16;
constexpr int ITILE  = 32;
constexpr int CHUNKS = NI / ITILE;
constexpr int GB     = B_ / BTILE;
constexpr int WROW   = DOUT * DK + 4;

__global__ __launch_bounds__(512)
void routing_pass(const float* __restrict__ x, const float* __restrict__ W,
                  const float* __restrict__ Vsum, float* __restrict__ s_out)
{
    __shared__ float W_s[NO * WROW];
    const int tid   = threadIdx.x;
    const int o     = tid & 31;
    const int bl    = tid >> 5;
    const int chunk = blockIdx.x & (CHUNKS - 1);
    const int gb    = blockIdx.x / CHUNKS;
    const int b     = gb * BTILE + bl;

    float vs[DOUT];
    {
        const float4* vp = (const float4*)(Vsum + (size_t)(b * NO + o) * DOUT);
        #pragma unroll
        for (int qq = 0; qq < 8; ++qq) {
            float4 t2 = vp[qq];
            vs[4*qq+0] = t2.x; vs[4*qq+1] = t2.y; vs[4*qq+2] = t2.z; vs[4*qq+3] = t2.w;
        }
    }
    float sacc[DOUT];
    #pragma unroll
    for (int d = 0; d < DOUT; ++d) sacc[d] = 0.f;

    const int o_ld = tid >> 4;
    const int lpos = tid & 15;

    for (int ii = 0; ii < ITILE; ++ii) {
        const int i = chunk * ITILE + ii;
        __syncthreads();
        const float4* wsrc = (const float4*)W + ((size_t)o_ld * NI + i) * (DOUT * DK / 4);
        #pragma unroll
        for (int jj = 0; jj < 8; ++jj) {
            const int f4pos = lpos + 16 * jj;
            float4 v = wsrc[f4pos];
            *(float4*)&W_s[o_ld * WROW + f4pos * 4] = v;
        }
        __syncthreads();

        const float4* xg = (const float4*)(x + ((size_t)b * NI + i) * DK);
        const float4 xr0 = xg[0], xr1 = xg[1], xr2 = xg[2], xr3 = xg[3];

        float u[DOUT];
        float logit = 0.f;
        const float* wrow = &W_s[o * WROW];
        #pragma unroll
        for (int d = 0; d < DOUT; ++d) {
            const float4 w0 = *(const float4*)(wrow + d * DK + 0);
            const float4 w1 = *(const float4*)(wrow + d * DK + 4);
            const float4 w2 = *(const float4*)(wrow + d * DK + 8);
            const float4 w3 = *(const float4*)(wrow + d * DK + 12);
            float acc;
            acc  = w0.x * xr0.x + w0.y * xr0.y + w0.z * xr0.z + w0.w * xr0.w;
            acc += w1.x * xr1.x + w1.y * xr1.y + w1.z * xr1.z + w1.w * xr1.w;
            acc += w2.x * xr2.x + w2.y * xr2.y + w2.z * xr2.z + w2.w * xr2.w;
            acc += w3.x * xr3.x + w3.y * xr3.y + w3.z * xr3.z + w3.w * xr3.w;
            u[d]  = acc;
            logit = fmaf(vs[d], acc, logit);
        }

        float m = logit;
        #pragma unroll
        for (int msk = 16; msk >= 1; msk >>= 1) m = fmaxf(m, __shfl_xor(m, msk));
        const float e = __expf(logit - m);
        float ssum = e;
        #pragma unroll
        for (int msk = 16; msk >= 1; msk >>= 1) ssum += __shfl_xor(ssum, msk);
        const float c = e / ssum;

        #pragma unroll
        for (int d = 0; d < DOUT; ++d) sacc[d] = fmaf(c, u[d], sacc[d]);
    }

    float* sp = s_out + (size_t)(b * NO + o) * DOUT;
    #pragma unroll
    for (int d = 0; d < DOUT; ++d) atomicAdd(&sp[d], sacc[d]);
}

// ============================================================
extern "C" void kernel_launch(void* const* d_in, const int* in_sizes, int n_in,
                              void* d_out, int out_size, void* d_ws, size_t ws_size,
                              hipStream_t stream)
{
    const float* x = (const float*)d_in[0];   // [B, NI, DK]
    const float* W = (const float*)d_in[1];   // [NO, NI, DOUT, DK]
    float* out = (float*)d_out;               // [B, NO, DOUT]

    float* s0 = (float*)d_ws;                         // 65536 floats each
    float* s1 = s0 + (size_t)B_ * NO * DOUT;
    float* s2 = s1 + (size_t)B_ * NO * DOUT;
    ushort* U = (ushort*)((char*)d_ws + (1 << 20));

    const size_t need = (1 << 20) + (size_t)B_ * NI * NO * DOUT * sizeof(ushort);

    // zero s0,s1,s2 in one shot
    hipMemsetAsync(d_ws, 0, (size_t)3 * B_ * NO * DOUT * sizeof(float), stream);

    if (ws_size >= need) {
        // r0 first: computes s0 from W (fp32-exact) AND warms L3 with W
        r0_sum<<<dim3(NO * R0_SEG), dim3(512), 0, stream>>>(x, W, s0);
        compute_uhat<<<dim3(NI), dim3(512), 0, stream>>>(x, W, U);
        routing_mid<1><<<dim3(B_ * BPB), dim3(256), 0, stream>>>(U, s0, s0, s1);
        routing_mid<2><<<dim3(B_ * BPB), dim3(256), 0, stream>>>(U, s0, s1, s2);
        squash_final<<<dim3(B_ * NO / 8), dim3(256), 0, stream>>>(s2, out);
    } else {
        // fallback: s = s0, Vsum = s1 (already zeroed)
        for (int r = 0; r < 3; ++r) {
            if (r > 0)
                hipMemsetAsync(s0, 0, (size_t)B_ * NO * DOUT * sizeof(float), stream);
            routing_pass<<<dim3(GB * CHUNKS), dim3(512), 0, stream>>>(x, W, s1, s0);
            squash_update<<<dim3(B_ * NO / 8), dim3(256), 0, stream>>>(s0, s1, out, r == 2);
        }
    }
}

// Round 2
// 470.867 us; speedup vs baseline: 1.5711x; 1.5711x over previous
//
#include <hip/hip_runtime.h>

#define B_    64
#define NI    2048
#define DK    16
#define NO    32
#define DOUT  32
#define EPSQ  1e-7f

typedef unsigned u32x2 __attribute__((ext_vector_type(2)));
typedef unsigned u32x4 __attribute__((ext_vector_type(4)));

// ---------- helpers ----------
__device__ __forceinline__ unsigned pack2_bf16(float a, float b) {
    unsigned ua = __float_as_uint(a);
    unsigned ub = __float_as_uint(b);
    ua = (ua + 0x7fffu + ((ua >> 16) & 1u)) >> 16;   // RNE
    ub = (ub + 0x7fffu + ((ub >> 16) & 1u)) >> 16;
    return ua | (ub << 16);
}
__device__ __forceinline__ float bf_lo(unsigned w) { return __uint_as_float(w << 16); }
__device__ __forceinline__ float bf_hi(unsigned w) { return __uint_as_float(w & 0xffff0000u); }

// ============================================================
// FAST PATH
// u_hat layout (bf16/ushort): idx = (((b*NI + i)*4 + j)*NO + o)*8 + e, d = j*8+e
// -> per (b,i): 4 rows of 256 ushorts (512B each), 2KB contiguous per (b,i).
// ============================================================

constexpr int WSTRIDE = 516;   // 512 + 4 pad: one-time LDS read conflicts only

// Produce u_hat = einsum('oidk,bik->boid') once. Block = one i, 512 threads.
// U is write-once/read-3x streaming -> nontemporal keeps W/x resident in L3.
__global__ __launch_bounds__(512)
void compute_uhat(const float* __restrict__ x, const float* __restrict__ W,
                  ushort* __restrict__ U)
{
    __shared__ float Ws[NO * WSTRIDE];   // 66048 B
    __shared__ float xs[B_ * DK];        // 4096 B
    const int i = blockIdx.x;
    const int t = threadIdx.x;

    // stage x[0:64, i, 0:16] (4 KB)
    if (t < 256) {
        const int b = t >> 2, k4 = t & 3;
        float4 v = *(const float4*)(x + ((size_t)b * NI + i) * DK + k4 * 4);
        *(float4*)&xs[b * DK + k4 * 4] = v;
    }

    // stage W[:, i, :, :] (64 KB) coalesced
    #pragma unroll
    for (int jj = 0; jj < 8; ++jj) {
        const int p  = t + 512 * jj;     // 0..4095
        const int oo = p >> 7;           // o
        const int cc = p & 127;          // float4 within o-row
        float4 v = ((const float4*)(W + ((size_t)oo * NI + i) * (DOUT * DK)))[cc];
        *(float4*)&Ws[oo * WSTRIDE + cc * 4] = v;
    }

    const int o  = t & 31;
    const int q  = (t >> 5) & 7;      // d = 4q .. 4q+3
    const int bh = t >> 8;            // 0/1

    __syncthreads();

    // one-time LDS -> regs: W[o,i,4q:4q+4,0:16] = 64 consecutive floats
    float w[64];
    {
        const float* wr = &Ws[o * WSTRIDE + q * 64];
        #pragma unroll
        for (int m = 0; m < 16; ++m) {
            float4 v = *(const float4*)(wr + 4 * m);
            w[4*m+0] = v.x; w[4*m+1] = v.y; w[4*m+2] = v.z; w[4*m+3] = v.w;
        }
    }

    const int j = q >> 1, half = q & 1;

    for (int bb = 0; bb < 32; ++bb) {
        const int b = bh * 32 + bb;
        const float4* xv = (const float4*)&xs[b * DK];
        const float4 x0 = xv[0], x1 = xv[1], x2 = xv[2], x3 = xv[3];

        float acc[4];
        #pragma unroll
        for (int dl = 0; dl < 4; ++dl) {
            const float* wr = &w[dl * 16];
            float a;
            a  = wr[0]  * x0.x + wr[1]  * x0.y + wr[2]  * x0.z + wr[3]  * x0.w;
            a += wr[4]  * x1.x + wr[5]  * x1.y + wr[6]  * x1.z + wr[7]  * x1.w;
            a += wr[8]  * x2.x + wr[9]  * x2.y + wr[10] * x2.z + wr[11] * x2.w;
            a += wr[12] * x3.x + wr[13] * x3.y + wr[14] * x3.z + wr[15] * x3.w;
            acc[dl] = a;
        }

        u32x2 pk;
        pk.x = pack2_bf16(acc[0], acc[1]);
        pk.y = pack2_bf16(acc[2], acc[3]);
        const size_t off = ((((size_t)b * NI + i) * 4 + j) * NO + o) * 8 + half * 4;
        __builtin_nontemporal_store(pk, (u32x2*)(U + off));   // 8-byte aligned
    }
}

// ============================================================
// r0 pass: s0[b,o,d] = (1/32) * sum_i u[b,i,o,d]   (c = 1/32 exactly)
// Pure streaming sum over U. Block = (b, i-segment of 128). 256 threads.
// Thread owns one uint4 column-group (j = c>>5, o = c&31, e=0..7) across
// its i's -> acc[8] in regs, coalesced NT loads, atomicAdd at the end.
// ============================================================
constexpr int SU_SEG = 16;             // i-segments per b
constexpr int SU_IPB = NI / SU_SEG;    // 128 i per block

__global__ __launch_bounds__(256)
void sum_u(const ushort* __restrict__ U, float* __restrict__ s0)
{
    const int t    = threadIdx.x;
    const int b    = blockIdx.x >> 4;
    const int iseg = blockIdx.x & (SU_SEG - 1);
    const int c    = t & 127;          // uint4 index within an i-row (128/row)
    const int half = t >> 7;           // row parity (i vs i+1)

    float acc[8];
    #pragma unroll
    for (int k = 0; k < 8; ++k) acc[k] = 0.f;

    // per (b,i): 128 u32x4 contiguous; two consecutive i-rows = 256 u32x4
    const u32x4* up = (const u32x4*)U
        + ((size_t)b * NI + (size_t)iseg * SU_IPB + half) * 128 + c;

    #pragma unroll 8
    for (int it = 0; it < SU_IPB / 2; ++it) {
        u32x4 w = __builtin_nontemporal_load(up);
        up += 256;
        acc[0] += bf_lo(w.x); acc[1] += bf_hi(w.x);
        acc[2] += bf_lo(w.y); acc[3] += bf_hi(w.y);
        acc[4] += bf_lo(w.z); acc[5] += bf_hi(w.z);
        acc[6] += bf_lo(w.w); acc[7] += bf_hi(w.w);
    }

    const int o = c & 31, j = c >> 5;       // d = j*8 + e
    float* sp = s0 + (size_t)b * (NO * DOUT) + o * DOUT + j * 8;
    #pragma unroll
    for (int k = 0; k < 8; ++k)
        atomicAdd(&sp[k], acc[k] * 0.03125f);
}

// ---------- per-i routing math (c from softmax, accumulate c*u) ----------
__device__ __forceinline__ void proc_one(const u32x4* cr, const float* vs, float* sacc)
{
    unsigned cw[16];
    #pragma unroll
    for (int jj = 0; jj < 4; ++jj) {
        cw[4*jj+0] = cr[jj].x; cw[4*jj+1] = cr[jj].y;
        cw[4*jj+2] = cr[jj].z; cw[4*jj+3] = cr[jj].w;
    }

    float l0 = 0.f, l1 = 0.f, l2 = 0.f, l3 = 0.f;
    #pragma unroll
    for (int m = 0; m < 16; m += 4) {
        const int d0 = (m >> 2) * 8;
        l0 = fmaf(vs[d0+0], bf_lo(cw[m+0]), l0);
        l0 = fmaf(vs[d0+1], bf_hi(cw[m+0]), l0);
        l1 = fmaf(vs[d0+2], bf_lo(cw[m+1]), l1);
        l1 = fmaf(vs[d0+3], bf_hi(cw[m+1]), l1);
        l2 = fmaf(vs[d0+4], bf_lo(cw[m+2]), l2);
        l2 = fmaf(vs[d0+5], bf_hi(cw[m+2]), l2);
        l3 = fmaf(vs[d0+6], bf_lo(cw[m+3]), l3);
        l3 = fmaf(vs[d0+7], bf_hi(cw[m+3]), l3);
    }
    const float logit = (l0 + l1) + (l2 + l3);

    // softmax over o = 32 lanes of this half-wave
    float mx = logit;
    #pragma unroll
    for (int msk = 16; msk >= 1; msk >>= 1) mx = fmaxf(mx, __shfl_xor(mx, msk));
    const float e = __expf(logit - mx);
    float ssum = e;
    #pragma unroll
    for (int msk = 16; msk >= 1; msk >>= 1) ssum += __shfl_xor(ssum, msk);
    const float c = e / ssum;

    #pragma unroll
    for (int m = 0; m < 16; ++m) {
        const int d0 = (m >> 2) * 8 + (m & 3) * 2;
        sacc[d0]     = fmaf(c, bf_lo(cw[m]), sacc[d0]);
        sacc[d0 + 1] = fmaf(c, bf_hi(cw[m]), sacc[d0 + 1]);
    }
}

// One routing iteration (r=1 or r=2) streaming u_hat.
// Prologue recomputes vs = squash(s0) [+ squash(s1) for R=2] in-block.
constexpr int BPB = 16;               // blocks per b
constexpr int NIB = NI / BPB / 16;    // 8 group-iterations (16 i per group)

template<int R>
__global__ __launch_bounds__(256)
void routing_mid(const ushort* __restrict__ U, const float* __restrict__ sA,
                 const float* __restrict__ sB, float* __restrict__ s_out)
{
    __shared__ float sblk[NO * DOUT];     // swizzled: (o,d) at [o*32 + ((d+o)&31)]
    __shared__ float vsh[NO][DOUT + 1];   // +1 pad -> conflict-free column reads
    const int t  = threadIdx.x;
    const int b  = blockIdx.x >> 4;
    const int i0 = (blockIdx.x & (BPB - 1)) * (NI / BPB);

    // ---- vs (running v sum) into vsh: thread = (oo = t>>3, dg = t&7) ----
    {
        const int oo = t >> 3;
        const int dg = t & 7;
        float4 sv = *(const float4*)(sA + ((size_t)b * NO + oo) * DOUT + dg * 4);
        float sq = sv.x*sv.x + sv.y*sv.y + sv.z*sv.z + sv.w*sv.w;
        #pragma unroll
        for (int msk = 4; msk >= 1; msk >>= 1) sq += __shfl_xor(sq, msk);
        float sc = sq / (1.f + sq) * rsqrtf(sq + EPSQ);
        float v0 = sv.x * sc, v1 = sv.y * sc, v2 = sv.z * sc, v3 = sv.w * sc;
        if (R == 2) {
            float4 s2v = *(const float4*)(sB + ((size_t)b * NO + oo) * DOUT + dg * 4);
            float sq2 = s2v.x*s2v.x + s2v.y*s2v.y + s2v.z*s2v.z + s2v.w*s2v.w;
            #pragma unroll
            for (int msk = 4; msk >= 1; msk >>= 1) sq2 += __shfl_xor(sq2, msk);
            float sc2 = sq2 / (1.f + sq2) * rsqrtf(sq2 + EPSQ);
            v0 += s2v.x * sc2; v1 += s2v.y * sc2; v2 += s2v.z * sc2; v3 += s2v.w * sc2;
        }
        vsh[oo][dg*4+0] = v0; vsh[oo][dg*4+1] = v1;
        vsh[oo][dg*4+2] = v2; vsh[oo][dg*4+3] = v3;
    }
    for (int n = t; n < NO * DOUT; n += 256) sblk[n] = 0.f;
    __syncthreads();

    const int o  = t & 31;
    const int hw = t >> 5;            // 0..7

    float vs[DOUT];
    #pragma unroll
    for (int d = 0; d < DOUT; ++d) vs[d] = vsh[o][d];

    float sacc[DOUT];
    #pragma unroll
    for (int d = 0; d < DOUT; ++d) sacc[d] = 0.f;

    // per (b,i): 4*NO u32x4's; row j at [j*NO]; i+1 is +4*NO
    const u32x4* up = (const u32x4*)U + ((size_t)b * NI + i0 + 2 * hw) * (4 * NO) + o;
    const size_t step = (size_t)16 * 4 * NO;   // advance i by 16

    u32x4 cur[8];
    #pragma unroll
    for (int jj = 0; jj < 4; ++jj) {
        cur[jj]     = __builtin_nontemporal_load(up + jj * NO);
        cur[4 + jj] = __builtin_nontemporal_load(up + 4 * NO + jj * NO);
    }
    up += step;

    for (int ii = 0; ii < NIB; ++ii) {
        u32x4 nxt[8];
        if (ii + 1 < NIB) {           // uniform branch
            #pragma unroll
            for (int jj = 0; jj < 4; ++jj) {
                nxt[jj]     = __builtin_nontemporal_load(up + jj * NO);
                nxt[4 + jj] = __builtin_nontemporal_load(up + 4 * NO + jj * NO);
            }
            up += step;
        }

        proc_one(&cur[0], vs, sacc);
        proc_one(&cur[4], vs, sacc);

        #pragma unroll
        for (int jj = 0; jj < 8; ++jj) cur[jj] = nxt[jj];
    }

    // reduce the wave's two half-waves (same (b,o), disjoint i)
    #pragma unroll
    for (int d = 0; d < DOUT; ++d) sacc[d] += __shfl_xor(sacc[d], 32);

    if ((t & 32) == 0) {
        #pragma unroll
        for (int d = 0; d < DOUT; ++d)
            atomicAdd(&sblk[o * DOUT + ((d + o) & 31)], sacc[d]);  // conflict-free
    }
    __syncthreads();

    float* sp = s_out + (size_t)b * NO * DOUT;
    for (int n = t; n < NO * DOUT; n += 256) {
        const int oo = n >> 5, ds = n & 31;
        const int dd = (ds - oo) & 31;
        atomicAdd(&sp[oo * DOUT + dd], sblk[n]);
    }
}

// final v = squash(s2) -> out
__global__ __launch_bounds__(256)
void squash_final(const float* __restrict__ s, float* __restrict__ out)
{
    const int tid  = threadIdx.x;
    const int pair = blockIdx.x * 8 + (tid >> 5);
    const int d    = tid & 31;
    const int idx  = pair * DOUT + d;

    const float val = s[idx];
    float sq = val * val;
    #pragma unroll
    for (int msk = 16; msk >= 1; msk >>= 1) sq += __shfl_xor(sq, msk);

    const float scale = sq / (1.f + sq) * rsqrtf(sq + EPSQ);
    out[idx] = val * scale;
}

// v = squash(s); Vsum += v; last iteration writes v to out.  (fallback path)
__global__ __launch_bounds__(256)
void squash_update(const float* __restrict__ s, float* __restrict__ Vsum,
                   float* __restrict__ out, int last)
{
    const int tid  = threadIdx.x;
    const int pair = blockIdx.x * 8 + (tid >> 5);
    const int d    = tid & 31;
    const int idx  = pair * DOUT + d;

    const float val = s[idx];
    float sq = val * val;
    #pragma unroll
    for (int msk = 16; msk >= 1; msk >>= 1) sq += __shfl_xor(sq, msk);

    const float scale = sq / (1.f + sq) * rsqrtf(sq + EPSQ);
    const float v = val * scale;

    if (last) out[idx] = v;
    else      Vsum[idx] += v;
}

// ============================================================
// FALLBACK PATH (fused recompute; used if ws too small)
// ============================================================
constexpr int BTILE  = 16;
constexpr int ITILE  = 32;
constexpr int CHUNKS = NI / ITILE;
constexpr int GB     = B_ / BTILE;
constexpr int WROW   = DOUT * DK + 4;

__global__ __launch_bounds__(512)
void routing_pass(const float* __restrict__ x, const float* __restrict__ W,
                  const float* __restrict__ Vsum, float* __restrict__ s_out)
{
    __shared__ float W_s[NO * WROW];
    const int tid   = threadIdx.x;
    const int o     = tid & 31;
    const int bl    = tid >> 5;
    const int chunk = blockIdx.x & (CHUNKS - 1);
    const int gb    = blockIdx.x / CHUNKS;
    const int b     = gb * BTILE + bl;

    float vs[DOUT];
    {
        const float4* vp = (const float4*)(Vsum + (size_t)(b * NO + o) * DOUT);
        #pragma unroll
        for (int qq = 0; qq < 8; ++qq) {
            float4 t2 = vp[qq];
            vs[4*qq+0] = t2.x; vs[4*qq+1] = t2.y; vs[4*qq+2] = t2.z; vs[4*qq+3] = t2.w;
        }
    }
    float sacc[DOUT];
    #pragma unroll
    for (int d = 0; d < DOUT; ++d) sacc[d] = 0.f;

    const int o_ld = tid >> 4;
    const int lpos = tid & 15;

    for (int ii = 0; ii < ITILE; ++ii) {
        const int i = chunk * ITILE + ii;
        __syncthreads();
        const float4* wsrc = (const float4*)W + ((size_t)o_ld * NI + i) * (DOUT * DK / 4);
        #pragma unroll
        for (int jj = 0; jj < 8; ++jj) {
            const int f4pos = lpos + 16 * jj;
            float4 v = wsrc[f4pos];
            *(float4*)&W_s[o_ld * WROW + f4pos * 4] = v;
        }
        __syncthreads();

        const float4* xg = (const float4*)(x + ((size_t)b * NI + i) * DK);
        const float4 xr0 = xg[0], xr1 = xg[1], xr2 = xg[2], xr3 = xg[3];

        float u[DOUT];
        float logit = 0.f;
        const float* wrow = &W_s[o * WROW];
        #pragma unroll
        for (int d = 0; d < DOUT; ++d) {
            const float4 w0 = *(const float4*)(wrow + d * DK + 0);
            const float4 w1 = *(const float4*)(wrow + d * DK + 4);
            const float4 w2 = *(const float4*)(wrow + d * DK + 8);
            const float4 w3 = *(const float4*)(wrow + d * DK + 12);
            float acc;
            acc  = w0.x * xr0.x + w0.y * xr0.y + w0.z * xr0.z + w0.w * xr0.w;
            acc += w1.x * xr1.x + w1.y * xr1.y + w1.z * xr1.z + w1.w * xr1.w;
            acc += w2.x * xr2.x + w2.y * xr2.y + w2.z * xr2.z + w2.w * xr2.w;
            acc += w3.x * xr3.x + w3.y * xr3.y + w3.z * xr3.z + w3.w * xr3.w;
            u[d]  = acc;
            logit = fmaf(vs[d], acc, logit);
        }

        float m = logit;
        #pragma unroll
        for (int msk = 16; msk >= 1; msk >>= 1) m = fmaxf(m, __shfl_xor(m, msk));
        const float e = __expf(logit - m);
        float ssum = e;
        #pragma unroll
        for (int msk = 16; msk >= 1; msk >>= 1) ssum += __shfl_xor(ssum, msk);
        const float c = e / ssum;

        #pragma unroll
        for (int d = 0; d < DOUT; ++d) sacc[d] = fmaf(c, u[d], sacc[d]);
    }

    float* sp = s_out + (size_t)(b * NO + o) * DOUT;
    #pragma unroll
    for (int d = 0; d < DOUT; ++d) atomicAdd(&sp[d], sacc[d]);
}

// ============================================================
extern "C" void kernel_launch(void* const* d_in, const int* in_sizes, int n_in,
                              void* d_out, int out_size, void* d_ws, size_t ws_size,
                              hipStream_t stream)
{
    const float* x = (const float*)d_in[0];   // [B, NI, DK]
    const float* W = (const float*)d_in[1];   // [NO, NI, DOUT, DK]
    float* out = (float*)d_out;               // [B, NO, DOUT]

    float* s0 = (float*)d_ws;                         // 65536 floats each
    float* s1 = s0 + (size_t)B_ * NO * DOUT;
    float* s2 = s1 + (size_t)B_ * NO * DOUT;
    ushort* U = (ushort*)((char*)d_ws + (1 << 20));

    const size_t need = (1 << 20) + (size_t)B_ * NI * NO * DOUT * sizeof(ushort);

    // zero s0,s1,s2 in one shot
    hipMemsetAsync(d_ws, 0, (size_t)3 * B_ * NO * DOUT * sizeof(float), stream);

    if (ws_size >= need) {
        compute_uhat<<<dim3(NI), dim3(512), 0, stream>>>(x, W, U);
        sum_u<<<dim3(B_ * SU_SEG), dim3(256), 0, stream>>>(U, s0);
        routing_mid<1><<<dim3(B_ * BPB), dim3(256), 0, stream>>>(U, s0, s0, s1);
        routing_mid<2><<<dim3(B_ * BPB), dim3(256), 0, stream>>>(U, s0, s1, s2);
        squash_final<<<dim3(B_ * NO / 8), dim3(256), 0, stream>>>(s2, out);
    } else {
        // fallback: s = s0, Vsum = s1 (already zeroed)
        for (int r = 0; r < 3; ++r) {
            if (r > 0)
                hipMemsetAsync(s0, 0, (size_t)B_ * NO * DOUT * sizeof(float), stream);
            routing_pass<<<dim3(GB * CHUNKS), dim3(512), 0, stream>>>(x, W, s1, s0);
            squash_update<<<dim3(B_ * NO / 8), dim3(256), 0, stream>>>(s0, s1, out, r == 2);
        }
    }
}